// Round 2
// baseline (12945.886 us; speedup 1.0000x reference)
//
#include <hip/hip_runtime.h>
#include <hip/hip_bf16.h>
#include <math.h>

#define D_    1024
#define DFF_  4096
#define LT_   2
#define HT_   16
#define C_    4
#define DC_   256
#define DFFC_ 1024
#define LC_   4
#define HC_   4
#define B_    2
#define T_    1024
#define VSZ_  32000

__device__ __forceinline__ float gelu_f(float x) {
  // jax.nn.gelu default (approximate=True, tanh form)
  const float c = 0.7978845608028654f;
  return 0.5f * x * (1.f + tanhf(c * (x + 0.044715f * x * x * x)));
}

// ---------------- embedding gather: x[b,t,:] = tok_emb[ids[b,t],:] ----------------
__global__ void embed_k(const int* __restrict__ ids, const float* __restrict__ emb,
                        float* __restrict__ X) {
  int bt = blockIdx.x;
  int id = ids[bt];
  const float* e = emb + (long)id * D_;
  float* x = X + (long)bt * D_;
  for (int i = threadIdx.x; i < D_; i += 256) x[i] = e[i];
}

// ---------------- rmsnorm: one block per row ----------------
// weight selected per row-group: wp = W + (row/rowsPerGroup)*wStride
__global__ __launch_bounds__(256) void rmsnorm_k(const float* __restrict__ Xi,
    float* __restrict__ Y, const float* __restrict__ W, int Dn,
    int rowsPerGroup, long wStride)
{
  int r = blockIdx.x;
  const float* xp = Xi + (long)r * Dn;
  float* yp = Y + (long)r * Dn;
  const float* wp = W + (long)(r / rowsPerGroup) * wStride;
  __shared__ float red[256];
  float s = 0.f;
  for (int i = threadIdx.x; i < Dn; i += 256) { float v = xp[i]; s += v * v; }
  red[threadIdx.x] = s;
  __syncthreads();
  for (int w = 128; w; w >>= 1) {
    if (threadIdx.x < w) red[threadIdx.x] += red[threadIdx.x + w];
    __syncthreads();
  }
  float scale = 1.f / sqrtf(red[0] / (float)Dn + 1e-6f);
  for (int i = threadIdx.x; i < Dn; i += 256)
    yp[i] = xp[i] * scale * wp[i];
}

// ---------------- RoPE in-place on (NB, T, nh, 64); one thread per (row, pair) ----------------
__global__ void rope_k(float* __restrict__ Xq, long total, int T, int nh) {
  long idx = (long)blockIdx.x * 256 + threadIdx.x;
  if (idx >= total) return;
  int i = (int)(idx & 31);
  long rest = idx >> 5;
  int h = (int)(rest % nh);
  rest /= nh;                     // = nb*T + t
  int t = (int)(rest % T);
  float inv = powf(10000.f, -(float)(2 * i) / 64.f);
  float f = (float)t * inv;
  float c = cosf(f), s = sinf(f);
  float* p = Xq + (rest * (long)nh + h) * 64;
  float x1 = p[i], x2 = p[i + 32];
  p[i]      = x1 * c - x2 * s;
  p[i + 32] = x2 * c + x1 * s;
}

// ---------------- causal attention, online softmax; one block per (b,h,q) row ----------------
// Q/K/V/O layout: (NB, T, nh, 64)
__global__ __launch_bounds__(256) void attn_k(const float* __restrict__ Q,
    const float* __restrict__ Kt, const float* __restrict__ Vt,
    float* __restrict__ O, int T, int nh, float scale)
{
  int qi = blockIdx.x, h = blockIdx.y;
  long b = blockIdx.z;
  int tid = threadIdx.x;
  long rs = (long)nh * 64;
  const float* qp = Q + (b * T + qi) * rs + h * 64;
  __shared__ float qv[64], ov[64], pr[256], red[256];
  if (tid < 64) { qv[tid] = qp[tid]; ov[tid] = 0.f; }
  __syncthreads();
  float m = -1e30f, l = 0.f;
  for (int k0 = 0; k0 <= qi; k0 += 256) {
    int jn = min(256, qi + 1 - k0);
    float s = -1e30f;
    if (tid < jn) {
      const float* kp = Kt + (b * T + k0 + tid) * rs + h * 64;
      float acc = 0.f;
#pragma unroll
      for (int d = 0; d < 64; d++) acc += qv[d] * kp[d];
      s = acc * scale;
    }
    red[tid] = s;
    __syncthreads();
#pragma unroll
    for (int w = 128; w; w >>= 1) {
      if (tid < w) red[tid] = fmaxf(red[tid], red[tid + w]);
      __syncthreads();
    }
    float nm = fmaxf(m, red[0]);
    __syncthreads();
    float p = (tid < jn) ? expf(s - nm) : 0.f;
    pr[tid] = p;
    red[tid] = p;
    __syncthreads();
#pragma unroll
    for (int w = 128; w; w >>= 1) {
      if (tid < w) red[tid] += red[tid + w];
      __syncthreads();
    }
    float csum = red[0];
    float alpha = expf(m - nm);   // first chunk: exp(-huge) == 0, harmless
    l = l * alpha + csum;
    if (tid < 64) {
      float acc = ov[tid] * alpha;
      const float* vb = Vt + (b * T + k0) * rs + h * 64 + tid;
      for (int j = 0; j < jn; j++) acc += pr[j] * vb[(long)j * rs];
      ov[tid] = acc;
    }
    m = nm;
    __syncthreads();
  }
  if (tid < 64) O[(b * T + qi) * rs + h * 64 + tid] = ov[tid] / l;
}

// ---------------- cross-column merge attention: one wave per (b,t,h), softmax over 4 columns ----------------
// Q/K/V/O layout: (C, B, T, HC, 64)
__global__ __launch_bounds__(64) void merge_attn_k(const float* __restrict__ Q,
    const float* __restrict__ Kt, const float* __restrict__ Vt,
    float* __restrict__ O, float scale)
{
  int bid = blockIdx.x;              // ((b*T + t)*HC + h)
  int h = bid & (HC_ - 1);
  int t = (bid >> 2) & (T_ - 1);
  int b = bid >> 12;
  int d = threadIdx.x;
  long base[C_];
  float q[C_], k[C_], v[C_];
#pragma unroll
  for (int c = 0; c < C_; c++) {
    base[c] = ((((long)c * B_ + b) * T_ + t) * HC_ + h) * 64 + d;
    q[c] = Q[base[c]]; k[c] = Kt[base[c]]; v[c] = Vt[base[c]];
  }
  float s[C_][C_];
#pragma unroll
  for (int i = 0; i < C_; i++)
#pragma unroll
    for (int j = 0; j < C_; j++) {
      float p = q[i] * k[j];
#pragma unroll
      for (int off = 32; off; off >>= 1) p += __shfl_xor(p, off);
      s[i][j] = p * scale;
    }
#pragma unroll
  for (int i = 0; i < C_; i++) {
    float mx = fmaxf(fmaxf(s[i][0], s[i][1]), fmaxf(s[i][2], s[i][3]));
    float e0 = expf(s[i][0] - mx), e1 = expf(s[i][1] - mx),
          e2 = expf(s[i][2] - mx), e3 = expf(s[i][3] - mx);
    float inv = 1.f / (e0 + e1 + e2 + e3);
    O[base[i]] = (e0 * v[0] + e1 * v[1] + e2 * v[2] + e3 * v[3]) * inv;
  }
}

// ---------------- transpose (C,B,T,DC) -> (B,T,C*DC) ----------------
__global__ void transpose_cs_k(const float* __restrict__ CS, float* __restrict__ X) {
  long idx = (long)blockIdx.x * 256 + threadIdx.x;   // < C*B*T*DC
  int d = (int)(idx & (DC_ - 1));
  long r = idx >> 8;                                  // c*(B*T) + bt
  int c = (int)(r / (B_ * T_));
  long bt = r % (B_ * T_);
  X[(bt * C_ + c) * DC_ + d] = CS[idx];
}

// ---------------- generic tiled GEMM: C = [resid +] [gelu(] A(f32 MxK) @ B(f32) [+bias] [)] ----------------
// BT_: B accessed as B[n*Kd + k] (i.e. A @ B^T). Otherwise B[k*N + n].
// Batched over blockIdx.z with element strides sA/sB/sC/sBias/sRes.
// M % 64 == 0, N % 64 == 0, Kd % 16 == 0 (all shapes here satisfy this).
template<bool BT_, bool GELU_>
__global__ __launch_bounds__(256) void gemm_k(
    const float* __restrict__ A, const float* __restrict__ Bw, float* __restrict__ Cp,
    const float* __restrict__ bias, const float* __restrict__ resid,
    int M, int N, int Kd,
    long sA, long sB, long sC, long sBias, long sRes)
{
  int z = blockIdx.z;
  A  += (long)z * sA;
  Bw += (long)z * sB;
  if (bias)  bias  += (long)z * sBias;
  if (resid) resid += (long)z * sRes;
  long cbase = (long)z * sC;

  int n0 = blockIdx.x * 64;
  int m0 = blockIdx.y * 64;
  int tid = threadIdx.x;
  int tx = tid & 15, ty = tid >> 4;

  __shared__ float As[16][65];   // +1 pad: kills 16-way bank conflict on stores
  __shared__ float Bs[16][65];

  float acc[4][4] = {};

  for (int k0 = 0; k0 < Kd; k0 += 16) {
#pragma unroll
    for (int u = 0; u < 4; u++) {
      int e = tid + u * 256;
      int mm = e >> 4, kk = e & 15;
      As[kk][mm] = A[(long)(m0 + mm) * Kd + (k0 + kk)];
    }
#pragma unroll
    for (int u = 0; u < 4; u++) {
      int e = tid + u * 256;
      if (BT_) {
        int nn = e >> 4, kk = e & 15;
        Bs[kk][nn] = Bw[(long)(n0 + nn) * Kd + (k0 + kk)];
      } else {
        int kk = e >> 6, nn = e & 63;
        Bs[kk][nn] = Bw[(long)(k0 + kk) * N + (n0 + nn)];
      }
    }
    __syncthreads();
#pragma unroll
    for (int kk = 0; kk < 16; kk++) {
      float a[4], b[4];
#pragma unroll
      for (int i = 0; i < 4; i++) a[i] = As[kk][ty * 4 + i];
#pragma unroll
      for (int j = 0; j < 4; j++) b[j] = Bs[kk][tx * 4 + j];
#pragma unroll
      for (int i = 0; i < 4; i++)
#pragma unroll
        for (int j = 0; j < 4; j++) acc[i][j] += a[i] * b[j];
    }
    __syncthreads();
  }

#pragma unroll
  for (int i = 0; i < 4; i++) {
    int mrow = m0 + ty * 4 + i;
#pragma unroll
    for (int j = 0; j < 4; j++) {
      int ncol = n0 + tx * 4 + j;
      float v = acc[i][j];
      if (bias) v += bias[ncol];
      if (GELU_) v = gelu_f(v);
      if (resid) v += resid[(long)mrow * N + ncol];
      Cp[cbase + (long)mrow * N + ncol] = v;
    }
  }
}

static inline void gemm_launch(hipStream_t st, bool bt, bool gelu,
    const float* A, const float* Bw, float* C, const float* bias, const float* resid,
    int M, int N, int Kd, long sA, long sB, long sC, long sBias, long sRes, int nz)
{
  dim3 g(N / 64, M / 64, nz), b(256, 1, 1);
  if (bt)
    gemm_k<true, false><<<g, b, 0, st>>>(A, Bw, C, bias, resid, M, N, Kd, sA, sB, sC, sBias, sRes);
  else if (gelu)
    gemm_k<false, true><<<g, b, 0, st>>>(A, Bw, C, bias, resid, M, N, Kd, sA, sB, sC, sBias, sRes);
  else
    gemm_k<false, false><<<g, b, 0, st>>>(A, Bw, C, bias, resid, M, N, Kd, sA, sB, sC, sBias, sRes);
}

extern "C" void kernel_launch(void* const* d_in, const int* in_sizes, int n_in,
                              void* d_out, int out_size, void* d_ws, size_t ws_size,
                              hipStream_t stream)
{
  (void)in_sizes; (void)n_in; (void)out_size; (void)ws_size;
  const int*   input_ids  = (const int*)  d_in[0];
  const float* tok_emb    = (const float*)d_in[1];
  const float* trunk_wq   = (const float*)d_in[2];
  const float* trunk_wk   = (const float*)d_in[3];
  const float* trunk_wv   = (const float*)d_in[4];
  const float* trunk_wo   = (const float*)d_in[5];
  const float* trunk_w1   = (const float*)d_in[6];
  const float* trunk_w2   = (const float*)d_in[7];
  const float* trunk_n1   = (const float*)d_in[8];
  const float* trunk_n2   = (const float*)d_in[9];
  const float* col_in_w   = (const float*)d_in[10];
  const float* col_in_b   = (const float*)d_in[11];
  const float* col_wq     = (const float*)d_in[12];
  const float* col_wk     = (const float*)d_in[13];
  const float* col_wv     = (const float*)d_in[14];
  const float* col_wo     = (const float*)d_in[15];
  const float* col_w1     = (const float*)d_in[16];
  const float* col_w2     = (const float*)d_in[17];
  const float* col_n1     = (const float*)d_in[18];
  const float* col_n2     = (const float*)d_in[19];
  const float* mrg_wq     = (const float*)d_in[20];
  const float* mrg_wk     = (const float*)d_in[21];
  const float* mrg_wv     = (const float*)d_in[22];
  const float* mrg_wo     = (const float*)d_in[23];
  const float* mrg_n      = (const float*)d_in[24];
  const float* out_proj   = (const float*)d_in[25];
  const float* final_norm = (const float*)d_in[26];

  // workspace layout (fp32): X,H,Q,K,V,CT,CS = 7 x 2M floats; FF aliases Q..CT (8M floats)
  // total = 14M floats = 56 MB
  const size_t M2 = (size_t)2 * 1024 * 1024;
  float* Xf  = (float*)d_ws;
  float* Hf  = Xf + M2;
  float* Qf  = Hf + M2;
  float* Kf  = Qf + M2;
  float* Vf  = Kf + M2;
  float* CTf = Vf + M2;
  float* CSf = CTf + M2;
  float* FFf = Qf;   // FF (B*T*DFF = 8M floats) lives only when Q/K/V/CT are dead

  const int BT = B_ * T_;            // 2048
  const float scale = 0.125f;        // 64^-0.5

  embed_k<<<BT, 256, 0, stream>>>(input_ids, tok_emb, Xf);

  // ---------------- trunk ----------------
  for (int l = 0; l < LT_; l++) {
    const float* wq = trunk_wq + (size_t)l * D_ * D_;
    const float* wk = trunk_wk + (size_t)l * D_ * D_;
    const float* wv = trunk_wv + (size_t)l * D_ * D_;
    const float* wo = trunk_wo + (size_t)l * D_ * D_;
    const float* w1 = trunk_w1 + (size_t)l * D_ * DFF_;
    const float* w2 = trunk_w2 + (size_t)l * DFF_ * D_;
    const float* n1 = trunk_n1 + (size_t)l * D_;
    const float* n2 = trunk_n2 + (size_t)l * D_;

    rmsnorm_k<<<BT, 256, 0, stream>>>(Xf, Hf, n1, D_, 1, 0);
    gemm_launch(stream, false, false, Hf, wq, Qf, nullptr, nullptr, BT, D_, D_, 0,0,0,0,0, 1);
    gemm_launch(stream, false, false, Hf, wk, Kf, nullptr, nullptr, BT, D_, D_, 0,0,0,0,0, 1);
    gemm_launch(stream, false, false, Hf, wv, Vf, nullptr, nullptr, BT, D_, D_, 0,0,0,0,0, 1);
    {
      long total = (long)BT * HT_ * 32;
      rope_k<<<(int)(total / 256), 256, 0, stream>>>(Qf, total, T_, HT_);
      rope_k<<<(int)(total / 256), 256, 0, stream>>>(Kf, total, T_, HT_);
    }
    attn_k<<<dim3(T_, HT_, B_), 256, 0, stream>>>(Qf, Kf, Vf, CTf, T_, HT_, scale);
    gemm_launch(stream, false, false, CTf, wo, Xf, nullptr, Xf, BT, D_, D_, 0,0,0,0,0, 1);
    rmsnorm_k<<<BT, 256, 0, stream>>>(Xf, Hf, n2, D_, 1, 0);
    gemm_launch(stream, false, true, Hf, w1, FFf, nullptr, nullptr, BT, DFF_, D_, 0,0,0,0,0, 1);
    gemm_launch(stream, false, false, FFf, w2, Xf, nullptr, Xf, BT, D_, DFF_, 0,0,0,0,0, 1);
  }

  // ---------------- column input projection: cs[c] = x @ col_in_w[c] + col_in_b[c] ----------------
  gemm_launch(stream, false, false, Xf, col_in_w, CSf, col_in_b, nullptr,
              BT, DC_, D_, 0, (long)D_ * DC_, (long)BT * DC_, DC_, 0, C_);

  // ---------------- column layers ----------------
  for (int l = 0; l < LC_; l++) {
    const float* cwq = col_wq + (size_t)l * DC_ * DC_;
    const float* cwk = col_wk + (size_t)l * DC_ * DC_;
    const float* cwv = col_wv + (size_t)l * DC_ * DC_;
    const float* cwo = col_wo + (size_t)l * DC_ * DC_;
    const float* cw1 = col_w1 + (size_t)l * DC_ * DFFC_;
    const float* cw2 = col_w2 + (size_t)l * DFFC_ * DC_;
    const long sW   = (long)LC_ * DC_ * DC_;
    const long sW1  = (long)LC_ * DC_ * DFFC_;
    const long sW2  = (long)LC_ * DFFC_ * DC_;
    const long sRow = (long)BT * DC_;

    rmsnorm_k<<<C_ * BT, 256, 0, stream>>>(CSf, Hf, col_n1 + (size_t)l * DC_, DC_, BT, (long)LC_ * DC_);
    gemm_launch(stream, false, false, Hf, cwq, Qf, nullptr, nullptr, BT, DC_, DC_, sRow, sW, sRow, 0, 0, C_);
    gemm_launch(stream, false, false, Hf, cwk, Kf, nullptr, nullptr, BT, DC_, DC_, sRow, sW, sRow, 0, 0, C_);
    gemm_launch(stream, false, false, Hf, cwv, Vf, nullptr, nullptr, BT, DC_, DC_, sRow, sW, sRow, 0, 0, C_);
    {
      long total = (long)C_ * BT * HC_ * 32;
      rope_k<<<(int)(total / 256), 256, 0, stream>>>(Qf, total, T_, HC_);
      rope_k<<<(int)(total / 256), 256, 0, stream>>>(Kf, total, T_, HC_);
    }
    attn_k<<<dim3(T_, HC_, C_ * B_), 256, 0, stream>>>(Qf, Kf, Vf, CTf, T_, HC_, scale);
    gemm_launch(stream, false, false, CTf, cwo, CSf, nullptr, CSf, BT, DC_, DC_, sRow, sW, sRow, 0, sRow, C_);
    rmsnorm_k<<<C_ * BT, 256, 0, stream>>>(CSf, Hf, col_n2 + (size_t)l * DC_, DC_, BT, (long)LC_ * DC_);
    gemm_launch(stream, false, true, Hf, cw1, FFf, nullptr, nullptr, BT, DFFC_, DC_,
                sRow, sW1, (long)BT * DFFC_, 0, 0, C_);
    gemm_launch(stream, false, false, FFf, cw2, CSf, nullptr, CSf, BT, DC_, DFFC_,
                (long)BT * DFFC_, sW2, sRow, 0, sRow, C_);

    if ((l + 1) % 2 == 0) {
      int mi = (l + 1) / 2 - 1;
      const float* mwq = mrg_wq + (size_t)mi * DC_ * DC_;
      const float* mwk = mrg_wk + (size_t)mi * DC_ * DC_;
      const float* mwv = mrg_wv + (size_t)mi * DC_ * DC_;
      const float* mwo = mrg_wo + (size_t)mi * DC_ * DC_;
      rmsnorm_k<<<C_ * BT, 256, 0, stream>>>(CSf, Hf, mrg_n + (size_t)mi * DC_, DC_, 1, 0);
      gemm_launch(stream, false, false, Hf, mwq, Qf, nullptr, nullptr, C_ * BT, DC_, DC_, 0,0,0,0,0, 1);
      gemm_launch(stream, false, false, Hf, mwk, Kf, nullptr, nullptr, C_ * BT, DC_, DC_, 0,0,0,0,0, 1);
      gemm_launch(stream, false, false, Hf, mwv, Vf, nullptr, nullptr, C_ * BT, DC_, DC_, 0,0,0,0,0, 1);
      merge_attn_k<<<BT * HC_, 64, 0, stream>>>(Qf, Kf, Vf, CTf, scale);
      gemm_launch(stream, false, false, CTf, mwo, CSf, nullptr, CSf, C_ * BT, DC_, DC_, 0,0,0,0,0, 1);
    }
  }

  // ---------------- head ----------------
  transpose_cs_k<<<(C_ * BT * DC_) / 256, 256, 0, stream>>>(CSf, Xf);
  gemm_launch(stream, false, false, Xf, out_proj, CTf, nullptr, nullptr, BT, D_, D_, 0,0,0,0,0, 1);
  rmsnorm_k<<<BT, 256, 0, stream>>>(CTf, Xf, final_norm, D_, 1, 0);
  // logits = normed @ tok_emb^T  (fp32 out)
  gemm_launch(stream, true, false, Xf, tok_emb, (float*)d_out, nullptr, nullptr, BT, VSZ_, D_, 0,0,0,0,0, 1);
}